// Round 2
// baseline (4390.635 us; speedup 1.0000x reference)
//
#include <hip/hip_runtime.h>
#include <hip/hip_bf16.h>
#include <cstdint>
#include <cstddef>

// nODE: 50 Euler steps of  x <- x*(1+dt*gamma) + tanh(x @ W^T + b)*dt
// Round 2 design:
//  - state = bf16 hi + bf16 lo (hi is the GEMM operand; hi+lo ~ fp32 accuracy)
//  - block = 64 rows x 512 cols (full N) -> A read exactly once per step
//  - in-place state update (block owns its rows) -> 64.5 MB footprint, L3-resident
//  - XOR k-chunk swizzle on staging -> conflict-free ds_read_b128
//  - 512 blocks x 512 threads (8 waves), LDS 72 KB -> 2 blocks/CU, full residency

#define D_DIM 512
#define BATCH_N 32768
#define NSTEPS 50

typedef __bf16 bf16x8 __attribute__((ext_vector_type(8)));
typedef float f32x4 __attribute__((ext_vector_type(4)));

typedef __attribute__((address_space(1))) const void gv_t;
typedef __attribute__((address_space(3))) void lv_t;

__device__ __forceinline__ float bf16_bits_to_f(unsigned short u) {
    union { unsigned int i; float f; } c;
    c.i = ((unsigned int)u) << 16;
    return c.f;
}
__device__ __forceinline__ unsigned short f_to_bf16_bits(float f) {
    union { float f; unsigned int i; } c;
    c.f = f;
    unsigned int u = c.i;
    unsigned int r = (u + 0x7fffu + ((u >> 16) & 1u)) >> 16;  // RNE
    return (unsigned short)r;
}

__global__ __launch_bounds__(256) void f32_to_bf16_vec4(
    const float* __restrict__ src, unsigned short* __restrict__ dst, int nv) {
    int i = blockIdx.x * blockDim.x + threadIdx.x;
    if (i < nv) {
        float4 v = ((const float4*)src)[i];
        ushort4 o;
        o.x = f_to_bf16_bits(v.x);
        o.y = f_to_bf16_bits(v.y);
        o.z = f_to_bf16_bits(v.z);
        o.w = f_to_bf16_bits(v.w);
        ((ushort4*)dst)[i] = o;
    }
}

// Split fp32 -> (hi, lo) bf16 pair: hi = bf16(v), lo = bf16(v - hi)
__global__ __launch_bounds__(256) void split_f32_hilo(
    const float* __restrict__ src, unsigned short* __restrict__ hi,
    unsigned short* __restrict__ lo, int nv) {
    int i = blockIdx.x * blockDim.x + threadIdx.x;
    if (i < nv) {
        float4 v = ((const float4*)src)[i];
        ushort4 h, l;
        h.x = f_to_bf16_bits(v.x); l.x = f_to_bf16_bits(v.x - bf16_bits_to_f(h.x));
        h.y = f_to_bf16_bits(v.y); l.y = f_to_bf16_bits(v.y - bf16_bits_to_f(h.y));
        h.z = f_to_bf16_bits(v.z); l.z = f_to_bf16_bits(v.z - bf16_bits_to_f(h.z));
        h.w = f_to_bf16_bits(v.w); l.w = f_to_bf16_bits(v.w - bf16_bits_to_f(h.w));
        ((ushort4*)hi)[i] = h;
        ((ushort4*)lo)[i] = l;
    }
}

// One Euler step, in-place on (Ahi, Alo).
//   y   = Ahi @ Wb^T            (bf16 MFMA, fp32 acc)
//   s   = hi + lo               (near-fp32 state)
//   o   = s*(1+dt*gamma) + dt*tanh(y + bias)
//   final==0: Ahi/Alo <- split(o)   final==1: Fout <- o (fp32)
__global__ __launch_bounds__(512, 4) void node_step(
    unsigned short* __restrict__ Ahi,         // bf16 [32768][512]
    unsigned short* __restrict__ Alo,         // bf16 [32768][512]
    const unsigned short* __restrict__ Wb,    // bf16 [512][512]
    const float* __restrict__ bias,           // [512]
    const float* __restrict__ gamma,          // [512]
    float* __restrict__ Fout,                 // fp32 out (used when final)
    int final_step)
{
    __shared__ unsigned short ldsA[64 * 64];    //  8 KB
    __shared__ unsigned short ldsB[512 * 64];   // 64 KB

    const int tid  = threadIdx.x;
    const int lane = tid & 63;
    const int w    = tid >> 6;        // wave 0..7 -> col block w*64
    const int l16  = lane & 15;
    const int quad = lane >> 4;
    const int bm   = blockIdx.x;      // 0..511, rows [bm*64, bm*64+64)

    const unsigned short* Ag = Ahi + (size_t)bm * 64 * D_DIM;

    // Staging geometry (both tiles share it):
    //   piece p = g*64 + lane; LDS slot j = p&7, row = p>>3; 16B per piece.
    //   XOR swizzle: LDS slot (row, j) holds global k-chunk  kc = j ^ (row&7),
    //   so lane fetches global (row, kc) and HW stores at base_g + lane*16.
    const int rowS = (w * 64 + lane) >> 3;            // 0..63
    const int kcS  = (lane & 7) ^ (rowS & 7);
    const unsigned short* agp = Ag + rowS * D_DIM + kcS * 8;
    const unsigned short* bgp = Wb + rowS * D_DIM + kcS * 8;  // + i*64 rows

    f32x4 acc[4][4];
    const f32x4 zero = {0.f, 0.f, 0.f, 0.f};
#pragma unroll
    for (int a = 0; a < 4; ++a)
#pragma unroll
        for (int b = 0; b < 4; ++b) acc[a][b] = zero;

    for (int kb = 0; kb < D_DIM; kb += 64) {
        __syncthreads();
        __builtin_amdgcn_global_load_lds(
            (gv_t*)(agp + kb), (lv_t*)((char*)ldsA + w * 1024), 16, 0, 0);
#pragma unroll
        for (int i = 0; i < 8; ++i)
            __builtin_amdgcn_global_load_lds(
                (gv_t*)(bgp + kb + i * 64 * D_DIM),
                (lv_t*)((char*)ldsB + (i * 8 + w) * 1024), 16, 0, 0);
        __syncthreads();

#pragma unroll
        for (int kh = 0; kh < 2; ++kh) {
            const int j8 = ((kh * 4 + quad) ^ (l16 & 7)) * 8;  // swizzled k-chunk
            bf16x8 af[4], bf[4];
#pragma unroll
            for (int t = 0; t < 4; ++t)
                af[t] = *reinterpret_cast<const bf16x8*>(
                    &ldsA[(t * 16 + l16) * 64 + j8]);
#pragma unroll
            for (int t = 0; t < 4; ++t)
                bf[t] = *reinterpret_cast<const bf16x8*>(
                    &ldsB[(w * 64 + t * 16 + l16) * 64 + j8]);
#pragma unroll
            for (int tm = 0; tm < 4; ++tm)
#pragma unroll
                for (int tn = 0; tn < 4; ++tn)
                    acc[tm][tn] = __builtin_amdgcn_mfma_f32_16x16x32_bf16(
                        af[tm], bf[tn], acc[tm][tn], 0, 0, 0);
        }
    }

    // Epilogue. C/D layout: col = lane&15 (+tn*16), row = quad*4 + r (+tm*16).
    const float dt = 1.0f / 50.0f;
    const int gr0 = bm * 64 + quad * 4;
    const int gc0 = w * 64 + l16;
#pragma unroll
    for (int tn = 0; tn < 4; ++tn) {
        const int col = gc0 + tn * 16;
        const float bc = bias[col];
        const float g1 = 1.0f + dt * gamma[col];
#pragma unroll
        for (int tm = 0; tm < 4; ++tm) {
#pragma unroll
            for (int r = 0; r < 4; ++r) {
                const int row = gr0 + tm * 16 + r;
                const size_t idx = (size_t)row * D_DIM + col;
                float y = acc[tm][tn][r] + bc;
                float e = __expf(2.0f * y);
                float th = 1.0f - 2.0f * __builtin_amdgcn_rcpf(e + 1.0f);
                float s = bf16_bits_to_f(Ahi[idx]) + bf16_bits_to_f(Alo[idx]);
                float o = s * g1 + dt * th;
                if (final_step) {
                    Fout[idx] = o;
                } else {
                    unsigned short h = f_to_bf16_bits(o);
                    Ahi[idx] = h;
                    Alo[idx] = f_to_bf16_bits(o - bf16_bits_to_f(h));
                }
            }
        }
    }
}

extern "C" void kernel_launch(void* const* d_in, const int* in_sizes, int n_in,
                              void* d_out, int out_size, void* d_ws, size_t ws_size,
                              hipStream_t stream) {
    const float* x  = (const float*)d_in[0];   // [32768][512]
    const float* W  = (const float*)d_in[1];   // [512][512]
    const float* bi = (const float*)d_in[2];   // [512]
    const float* ga = (const float*)d_in[3];   // [512]

    uint8_t* ws = (uint8_t*)d_ws;
    const size_t W_BYTES  = (size_t)1 << 19;              // 512KB slot
    const size_t A_BYTES  = (size_t)BATCH_N * D_DIM * 2;  // 32MB

    unsigned short* Wb  = (unsigned short*)ws;
    unsigned short* Ahi = (unsigned short*)(ws + W_BYTES);
    unsigned short* Alo = (unsigned short*)(ws + W_BYTES + A_BYTES);
    // total ws use: 64.5 MB

    f32_to_bf16_vec4<<<256, 256, 0, stream>>>(W, Wb, 262144 / 4);
    split_f32_hilo<<<16384, 256, 0, stream>>>(x, Ahi, Alo, 16777216 / 4);

    for (int s = 1; s <= NSTEPS; ++s) {
        const int fin = (s == NSTEPS) ? 1 : 0;
        node_step<<<dim3(512), dim3(512), 0, stream>>>(
            Ahi, Alo, Wb, bi, ga, (float*)d_out, fin);
    }
}

// Round 3
// 1947.669 us; speedup vs baseline: 2.2543x; 2.2543x over previous
//
#include <hip/hip_runtime.h>
#include <hip/hip_bf16.h>
#include <cstdint>
#include <cstddef>

// nODE: 50 Euler steps of  x <- x*(1+dt*gamma) + dt*tanh(x @ W^T + b)
// Round 3: PERSISTENT-STATE kernel. out[m,:] depends only on A[m,:], so each
// block owns 64 rows and runs all 50 steps internally:
//   - state fp32 in VGPRs (C-layout aligned, 64/lane)
//   - state-hi bf16 in LDS (XOR-swizzled) = next step's MFMA A operand
//   - W bf16 streamed from L2 in 32-k slices, double-buffered global_load_lds
// Global traffic for the whole run: x in (64MB) + out (64MB) + W (~1MB).

#define D_DIM 512
#define BATCH_N 32768
#define NSTEPS 50

typedef __bf16 bf16x8 __attribute__((ext_vector_type(8)));
typedef float f32x4 __attribute__((ext_vector_type(4)));

typedef __attribute__((address_space(1))) const void gv_t;
typedef __attribute__((address_space(3))) void lv_t;

__device__ __forceinline__ float bf16_bits_to_f(unsigned short u) {
    union { unsigned int i; float f; } c;
    c.i = ((unsigned int)u) << 16;
    return c.f;
}
__device__ __forceinline__ unsigned short f_to_bf16_bits(float f) {
    union { float f; unsigned int i; } c;
    c.f = f;
    unsigned int u = c.i;
    unsigned int r = (u + 0x7fffu + ((u >> 16) & 1u)) >> 16;  // RNE
    return (unsigned short)r;
}

__global__ __launch_bounds__(256) void f32_to_bf16_vec4(
    const float* __restrict__ src, unsigned short* __restrict__ dst, int nv) {
    int i = blockIdx.x * blockDim.x + threadIdx.x;
    if (i < nv) {
        float4 v = ((const float4*)src)[i];
        ushort4 o;
        o.x = f_to_bf16_bits(v.x);
        o.y = f_to_bf16_bits(v.y);
        o.z = f_to_bf16_bits(v.z);
        o.w = f_to_bf16_bits(v.w);
        ((ushort4*)dst)[i] = o;
    }
}

// Persistent 50-step integrator. Block bm owns rows [bm*64, bm*64+64).
// 512 threads = 8 waves; wave w owns cols [w*64, w*64+64).
__global__ __launch_bounds__(512, 2) void node_persist(
    const float* __restrict__ X,              // fp32 [32768][512]
    const unsigned short* __restrict__ Wb,    // bf16 [512][512] (row j, col k)
    const float* __restrict__ bias,           // [512]
    const float* __restrict__ gamma,          // [512]
    float* __restrict__ Fout)                 // fp32 [32768][512]
{
    __shared__ unsigned short ldsA[64 * 512];       // 64 KB, swizzled state-hi
    __shared__ unsigned short ldsB[2][512 * 32];    // 2 x 32 KB, W k-slices

    const int tid  = threadIdx.x;
    const int lane = tid & 63;
    const int w    = tid >> 6;        // wave 0..7
    const int l16  = lane & 15;
    const int quad = lane >> 4;
    const int bm   = blockIdx.x;      // 0..511
    const float dt = 1.0f / 50.0f;

    const int r0 = quad * 4;          // row = r0 + tm*16 + r
    const int c0 = w * 64 + l16;      // col = c0 + tn*16

    // Per-lane column constants (loaded once for all 50 steps).
    float bc[4], g1[4];
#pragma unroll
    for (int tn = 0; tn < 4; ++tn) {
        bc[tn] = bias[c0 + tn * 16];
        g1[tn] = 1.0f + dt * gamma[c0 + tn * 16];
    }

    // Load initial state (fp32) into registers, C-layout aligned.
    float s[4][4][4];
#pragma unroll
    for (int tm = 0; tm < 4; ++tm)
#pragma unroll
        for (int tn = 0; tn < 4; ++tn)
#pragma unroll
            for (int r = 0; r < 4; ++r) {
                const int row = r0 + tm * 16 + r;
                const int col = c0 + tn * 16;
                s[tm][tn][r] = X[(size_t)(bm * 64 + row) * D_DIM + col];
            }

    // Write initial state-hi (bf16) into swizzled ldsA.
    // Layout: element (row, col) lives at row*512 + ((col>>3)^(row&63))*8 + (col&7).
#pragma unroll
    for (int tm = 0; tm < 4; ++tm)
#pragma unroll
        for (int tn = 0; tn < 4; ++tn)
#pragma unroll
            for (int r = 0; r < 4; ++r) {
                const int row = r0 + tm * 16 + r;
                const int col = c0 + tn * 16;
                const int a = row * 512 + (((col >> 3) ^ (row & 63)) << 3) + (col & 7);
                ldsA[a] = f_to_bf16_bits(s[tm][tn][r]);
            }

    // B staging geometry: slice = W[0:512][kb*32 : kb*32+32] -> 2048 pieces of
    // 16B. Piece p = g*64 + lane (g = i*8 + w, i=0..3): row = p>>2, slot j = p&3,
    // global k-chunk kc = j ^ swzB(row), swzB(row) = (row ^ (row>>2)) & 3.
    int goff[4], loff[4];
#pragma unroll
    for (int i = 0; i < 4; ++i) {
        const int g = i * 8 + w;
        const int p = g * 64 + lane;
        const int row = p >> 2;
        const int j = p & 3;
        const int kc = j ^ ((row ^ (row >> 2)) & 3);
        goff[i] = row * D_DIM + kc * 8;   // elements; + kb*32 per slice
        loff[i] = g * 1024;               // bytes within a 32 KB buffer
    }

    // Prime buffer 0 with kb=0.
#pragma unroll
    for (int i = 0; i < 4; ++i)
        __builtin_amdgcn_global_load_lds(
            (gv_t*)(Wb + goff[i]),
            (lv_t*)((char*)ldsB[0] + loff[i]), 16, 0, 0);

    f32x4 acc[4][4];
    const f32x4 zero = {0.f, 0.f, 0.f, 0.f};
#pragma unroll
    for (int a = 0; a < 4; ++a)
#pragma unroll
        for (int b = 0; b < 4; ++b) acc[a][b] = zero;

    // B-fragment read addresses (row fixed per t; chunk = quad ^ swzB(row)).
    int boff[4];
#pragma unroll
    for (int t = 0; t < 4; ++t) {
        const int rowb = w * 64 + t * 16 + l16;
        const int chunk = quad ^ ((rowb ^ (rowb >> 2)) & 3);
        boff[t] = rowb * 32 + chunk * 8;
    }

    for (int idx = 0; idx < NSTEPS * 16; ++idx) {
        const int cur = idx & 1;
        const int kb = idx & 15;

        __syncthreads();   // staging(cur) landed; all waves done with buf[cur^1]

        if (idx + 1 < NSTEPS * 16) {
            const int nkb = (idx + 1) & 15;
#pragma unroll
            for (int i = 0; i < 4; ++i)
                __builtin_amdgcn_global_load_lds(
                    (gv_t*)(Wb + goff[i] + nkb * 32),
                    (lv_t*)((char*)ldsB[cur ^ 1] + loff[i]), 16, 0, 0);
        }

        // Fragments for this 32-k slice.
        bf16x8 af[4], bf[4];
#pragma unroll
        for (int t = 0; t < 4; ++t) {
            const int rowa = t * 16 + l16;
            const int chunk = (kb * 4 + quad) ^ (rowa & 63);
            af[t] = *reinterpret_cast<const bf16x8*>(&ldsA[rowa * 512 + chunk * 8]);
        }
#pragma unroll
        for (int t = 0; t < 4; ++t)
            bf[t] = *reinterpret_cast<const bf16x8*>(&ldsB[cur][boff[t]]);

#pragma unroll
        for (int tm = 0; tm < 4; ++tm)
#pragma unroll
            for (int tn = 0; tn < 4; ++tn)
                acc[tm][tn] = __builtin_amdgcn_mfma_f32_16x16x32_bf16(
                    af[tm], bf[tn], acc[tm][tn], 0, 0, 0);

        if (kb == 15) {
            const int step = idx >> 4;
            // Euler update in registers.
#pragma unroll
            for (int tm = 0; tm < 4; ++tm)
#pragma unroll
                for (int tn = 0; tn < 4; ++tn) {
#pragma unroll
                    for (int r = 0; r < 4; ++r) {
                        float y = acc[tm][tn][r] + bc[tn];
                        float e = __expf(2.0f * y);
                        float th = 1.0f - 2.0f * __builtin_amdgcn_rcpf(e + 1.0f);
                        s[tm][tn][r] = s[tm][tn][r] * g1[tn] + dt * th;
                    }
                    acc[tm][tn] = zero;
                }

            if (step < NSTEPS - 1) {
                __syncthreads();   // all waves done reading ldsA this step
#pragma unroll
                for (int tm = 0; tm < 4; ++tm)
#pragma unroll
                    for (int tn = 0; tn < 4; ++tn)
#pragma unroll
                        for (int r = 0; r < 4; ++r) {
                            const int row = r0 + tm * 16 + r;
                            const int col = c0 + tn * 16;
                            const int a = row * 512 +
                                (((col >> 3) ^ (row & 63)) << 3) + (col & 7);
                            ldsA[a] = f_to_bf16_bits(s[tm][tn][r]);
                        }
            } else {
                // Final step: write fp32 output.
#pragma unroll
                for (int tm = 0; tm < 4; ++tm)
#pragma unroll
                    for (int tn = 0; tn < 4; ++tn)
#pragma unroll
                        for (int r = 0; r < 4; ++r) {
                            const int row = r0 + tm * 16 + r;
                            const int col = c0 + tn * 16;
                            Fout[(size_t)(bm * 64 + row) * D_DIM + col] =
                                s[tm][tn][r];
                        }
            }
        }
    }
}

extern "C" void kernel_launch(void* const* d_in, const int* in_sizes, int n_in,
                              void* d_out, int out_size, void* d_ws, size_t ws_size,
                              hipStream_t stream) {
    const float* x  = (const float*)d_in[0];   // [32768][512]
    const float* W  = (const float*)d_in[1];   // [512][512]
    const float* bi = (const float*)d_in[2];   // [512]
    const float* ga = (const float*)d_in[3];   // [512]

    unsigned short* Wb = (unsigned short*)d_ws;   // 512 KB

    f32_to_bf16_vec4<<<256, 256, 0, stream>>>(W, Wb, 262144 / 4);
    node_persist<<<dim3(512), dim3(512), 0, stream>>>(
        x, Wb, bi, ga, (float*)d_out);
}